// Round 1
// 121.935 us; speedup vs baseline: 1.0326x; 1.0326x over previous
//
#include <hip/hip_runtime.h>

// B=4, T=4096, E=1024, H=64.
// out = Q @ M_b,  M_b = (1/32) * K_b^T V_b,  Q/K/V = idx@W + b   (linear attention:
// reference applies no mask/softmax). Scale folded into Wk/bk.
//
// R8: qkv BM=32 (R=2 row-frags/wave halves L2 weight re-read 393->197MB), 2-deep
// register B prefetch (cover ~200cy L2 latency at 2 waves/SIMD), grid 512
// (2 blocks/CU, 66KB LDS each). Tail fused: ktv atomicAdds fp32 M (64KB, zeroed
// in prep since ws is poisoned); qm converts M->bf16 fragments in LDS. 4 kernels.

typedef __attribute__((ext_vector_type(8))) short bf16x8;   // 8 bf16 = 4 VGPRs
typedef __attribute__((ext_vector_type(4))) float f32x4;    // MFMA C/D

#define MFMA16(a, b, c) __builtin_amdgcn_mfma_f32_16x16x32_bf16((a), (b), (c), 0, 0, 0)

__device__ __forceinline__ unsigned short f2bf(float f) {
    unsigned int u = __float_as_uint(f);
    u += 0x7fffu + ((u >> 16) & 1u);          // round-to-nearest-even
    return (unsigned short)(u >> 16);
}

// ---------------------------------------------------------------------------
// K0: weights -> MFMA-fragment order, plus zero the M accumulator (ws is
// POISONED between iterations, so the atomic target must be cleared by us).
// Chunk index t = (kk*12 + nt)*64 + lane holds 8 bf16:
//   W^T[n][k], n = nt*16 + (lane&15), k = kk*32 + (lane>>4)*8 + j.
// n<64 -> Wq, n<128 -> Wk * 1/32, else Wv.   (W is [k][h] in memory)
__global__ void prep(const float* __restrict__ Wq, const float* __restrict__ Wk,
                     const float* __restrict__ Wv, unsigned short* __restrict__ WB,
                     float* __restrict__ Mf) {
    int t = blockIdx.x * 256 + threadIdx.x;   // 96 blocks -> 24576 chunks
    if (t < 16384) Mf[t] = 0.f;               // 4 * 64 * 64 fp32 accumulator
    int kki = t / 768;
    int rem = t - kki * 768;
    int nt = rem >> 6, lane = rem & 63;
    int n = nt * 16 + (lane & 15);
    int kb = kki * 32 + ((lane >> 4) * 8);
    int mm = n >> 6, h = n & 63;
    const float* W = (mm == 0) ? Wq : (mm == 1) ? Wk : Wv;
    float sc = (mm == 1) ? 0.03125f : 1.0f;
    bf16x8 v;
    #pragma unroll
    for (int j = 0; j < 8; j++) v[j] = (short)f2bf(W[(size_t)(kb + j) * 64 + h] * sc);
    *(bf16x8*)(WB + (size_t)t * 8) = v;
}

// ---------------------------------------------------------------------------
// K1: fused QKV projection.
// Block = 32 rows (128KB of idx), 4 waves; grid 512 (2 blocks/CU, 8 waves/CU).
// Each wave owns 2 row-frags x 3 col-frags (Q,K,V) -> every B fragment loaded
// from L2 feeds 2 MFMAs (B L2 traffic = 393MB / R, R=2 -> 197MB).
// Per kk: 2 A ds_read_b128 (1 ahead) + 3 B 1KB L2 loads (2-deep register
// pipeline, issued 2 kk ahead) + 6 MFMAs.
// Epilogue: accs -> LDS (reusing As) -> coalesced 16B/lane stores of Q/Kt/Vt.
__global__ __launch_bounds__(256, 2) void qkv(
    const float* __restrict__ idx, const unsigned short* __restrict__ WB,
    const float* __restrict__ bq, const float* __restrict__ bk, const float* __restrict__ bv,
    unsigned short* __restrict__ Q, unsigned short* __restrict__ Kt,
    unsigned short* __restrict__ Vt) {
    __shared__ unsigned short As[32 * 1032];       // 66 KB (stride 1032 -> 2-way banks)
    const int lane = threadIdx.x & 63, w = threadIdx.x >> 6;
    const int r0 = blockIdx.x * 32;

    // ---- stage: contiguous 32KB per wave (8 rows) ----
    const float* src = idx + (size_t)(r0 + w * 8) * 1024;
    #pragma unroll
    for (int batch = 0; batch < 4; batch++) {
        float4 v[8];
        #pragma unroll
        for (int j = 0; j < 8; j++)
            v[j] = *(const float4*)(src + (size_t)(batch * 8 + j) * 256 + lane * 4);
        #pragma unroll
        for (int j = 0; j < 8; j++) {
            int i   = batch * 8 + j;
            int row = w * 8 + (i >> 2);            // 4 chunks of 256 floats per row
            int k   = (i & 3) * 256 + lane * 4;
            unsigned int lo = ((unsigned int)f2bf(v[j].y) << 16) | f2bf(v[j].x);
            unsigned int hi = ((unsigned int)f2bf(v[j].w) << 16) | f2bf(v[j].z);
            uint2 p; p.x = lo; p.y = hi;
            *(uint2*)(As + (size_t)row * 1032 + k) = p;
        }
    }
    __syncthreads();

    // ---- compute: B 2 kk ahead in regs, A 1 kk ahead ----
    const f32x4 z4 = {0.f, 0.f, 0.f, 0.f};
    f32x4 acc[2][3] = {{z4, z4, z4}, {z4, z4, z4}};

    const unsigned short* a_base0 = As + (size_t)(lane & 15) * 1032 + ((lane >> 4) * 8);
    const unsigned short* a_base1 = a_base0 + 16 * 1032;
    bf16x8 a_c[2], b0[3], b1[3], b2[3];
    a_c[0] = *(const bf16x8*)a_base0;
    a_c[1] = *(const bf16x8*)a_base1;
    {
        const unsigned short* Bp0 = WB + (size_t)(lane * 8);
        const unsigned short* Bp1 = WB + (size_t)(12 * 64 + lane) * 8;
        #pragma unroll
        for (int j = 0; j < 3; j++) {
            b0[j] = *(const bf16x8*)(Bp0 + (w + j * 4) * 512);
            b1[j] = *(const bf16x8*)(Bp1 + (w + j * 4) * 512);
            b2[j] = b1[j];
        }
    }
    for (int kk = 0; kk < 32; kk++) {
        bf16x8 na0 = a_c[0], na1 = a_c[1];
        if (kk < 30) {
            const unsigned short* Bp = WB + (size_t)(((kk + 2) * 12) * 64 + lane) * 8;
            #pragma unroll
            for (int j = 0; j < 3; j++) b2[j] = *(const bf16x8*)(Bp + (w + j * 4) * 512);
        }
        if (kk < 31) {
            na0 = *(const bf16x8*)(a_base0 + (kk + 1) * 32);
            na1 = *(const bf16x8*)(a_base1 + (kk + 1) * 32);
        }
        #pragma unroll
        for (int j = 0; j < 3; j++) {
            acc[0][j] = MFMA16(a_c[0], b0[j], acc[0][j]);
            acc[1][j] = MFMA16(a_c[1], b0[j], acc[1][j]);
        }
        #pragma unroll
        for (int j = 0; j < 3; j++) { b0[j] = b1[j]; b1[j] = b2[j]; }
        a_c[0] = na0; a_c[1] = na1;
    }

    // ---- epilogue via LDS transpose (As is dead) ----
    __syncthreads();                               // all A reads done
    unsigned short* Lq = As;                       // [32][64] row-major (2048)
    unsigned short* Lk = As + 2048;                // [64][32] h-major  (2048)
    unsigned short* Lv = As + 4096;                // [64][32] h-major  (2048)
    const int h     = w * 16 + (lane & 15);
    const int rbase = (lane >> 4) * 4;             // + reg
    {
        float bias0 = bq[h], bias1 = bk[h] * 0.03125f, bias2 = bv[h];
        #pragma unroll
        for (int rf = 0; rf < 2; rf++) {
            #pragma unroll
            for (int reg = 0; reg < 4; reg++) {
                int r = rf * 16 + rbase + reg;
                Lq[r * 64 + h] = f2bf(acc[rf][0][reg] + bias0);
                Lk[h * 32 + r] = f2bf(acc[rf][1][reg] + bias1);
                Lv[h * 32 + r] = f2bf(acc[rf][2][reg] + bias2);
            }
        }
    }
    __syncthreads();
    {
        const int tt = threadIdx.x;
        // Q: [32 rows][64 h], fully coalesced 16B/lane
        int qr = tt >> 3, qh = (tt & 7) * 8;
        *(uint4*)(Q + (size_t)(r0 + qr) * 64 + qh) = *(const uint4*)(Lq + qr * 64 + qh);
        // Kt/Vt: [h][t], 16B/lane, 4 lanes per h (64B segments)
        int b = r0 >> 12, t0 = r0 & 4095;
        int hh = tt >> 2, tc = (tt & 3) * 8;
        *(uint4*)(Kt + (size_t)b * 262144 + hh * 4096 + t0 + tc) =
            *(const uint4*)(Lk + hh * 32 + tc);
        *(uint4*)(Vt + (size_t)b * 262144 + hh * 4096 + t0 + tc) =
            *(const uint4*)(Lv + hh * 32 + tc);
    }
}

// ---------------------------------------------------------------------------
// K2: M accumulation, fused reduce: per 128-t chunk compute Kt_chunk @ Vt_chunk^T
// in fp32 MFMA accs, then atomicAdd into Mf[b][h1][h2] (device-scope fp32).
// 128 blocks, 16 atomics/lane -> 524K atomics over 16K addresses.
__global__ __launch_bounds__(256) void ktv(
    const unsigned short* __restrict__ Kt, const unsigned short* __restrict__ Vt,
    float* __restrict__ Mf) {
    const int lane = threadIdx.x & 63, wave = threadIdx.x >> 6;
    const int c = blockIdx.x, b = blockIdx.y;
    const unsigned short* Kb = Kt + (size_t)b * 262144;
    const unsigned short* Vb = Vt + (size_t)b * 262144;
    const f32x4 z4 = {0.f, 0.f, 0.f, 0.f};
    f32x4 acc[4] = {z4, z4, z4, z4};
    const int m  = 16 * wave + (lane & 15);
    const int tq = (lane >> 4) * 8;
    #pragma unroll
    for (int it = 0; it < 4; it++) {
        int t0 = c * 128 + it * 32 + tq;
        bf16x8 a = *(const bf16x8*)&Kb[(size_t)m * 4096 + t0];
        #pragma unroll
        for (int nt = 0; nt < 4; nt++) {
            bf16x8 bb = *(const bf16x8*)&Vb[(size_t)(nt * 16 + (lane & 15)) * 4096 + t0];
            acc[nt] = MFMA16(a, bb, acc[nt]);
        }
    }
    float* P = Mf + (size_t)b * 4096;
    const int rowb = 16 * wave + (lane >> 4) * 4;
    #pragma unroll
    for (int nt = 0; nt < 4; nt++)
        #pragma unroll
        for (int reg = 0; reg < 4; reg++)
            atomicAdd(&P[(rowb + reg) * 64 + nt * 16 + (lane & 15)], acc[nt][reg]);
}

// ---------------------------------------------------------------------------
// K3: out[r][h2] = Q[r][:] @ M_b[:, h2], fp32 out. M converted fp32->bf16
// fragments in LDS per block (transposed layout [h2][h1], stride 72 shorts:
// 36 dwords % 32 = 4 -> 2-way banks, free).
__global__ __launch_bounds__(256) void qm(
    const unsigned short* __restrict__ Q, const float* __restrict__ Mf,
    float* __restrict__ out) {
    __shared__ unsigned short Lm[64 * 72];
    const int lane = threadIdx.x & 63, wave = threadIdx.x >> 6;
    const int r0 = blockIdx.x * 64;
    const int b  = r0 >> 12;
    {
        const int tt = threadIdx.x;
        int h1 = tt >> 2, h2c = (tt & 3) * 16;
        const float* Mp = Mf + (size_t)b * 4096 + h1 * 64 + h2c;
        float vals[16];
        *(float4*)(vals + 0)  = *(const float4*)(Mp + 0);
        *(float4*)(vals + 4)  = *(const float4*)(Mp + 4);
        *(float4*)(vals + 8)  = *(const float4*)(Mp + 8);
        *(float4*)(vals + 12) = *(const float4*)(Mp + 12);
        #pragma unroll
        for (int u = 0; u < 16; u++) Lm[(h2c + u) * 72 + h1] = f2bf(vals[u]);
    }
    __syncthreads();
    const f32x4 z4 = {0.f, 0.f, 0.f, 0.f};
    f32x4 acc[4] = {z4, z4, z4, z4};
    const int rr = r0 + 16 * wave + (lane & 15);
    const int kq = (lane >> 4) * 8;
    #pragma unroll
    for (int ks = 0; ks < 2; ks++) {
        int k0 = ks * 32;
        bf16x8 a = *(const bf16x8*)&Q[(size_t)rr * 64 + k0 + kq];
        #pragma unroll
        for (int nt = 0; nt < 4; nt++) {
            bf16x8 bb = *(const bf16x8*)&Lm[(size_t)(nt * 16 + (lane & 15)) * 72 + k0 + kq];
            acc[nt] = MFMA16(a, bb, acc[nt]);
        }
    }
    const int rowb = r0 + 16 * wave + (lane >> 4) * 4;
    #pragma unroll
    for (int nt = 0; nt < 4; nt++)
        #pragma unroll
        for (int reg = 0; reg < 4; reg++)
            out[(size_t)(rowb + reg) * 64 + nt * 16 + (lane & 15)] = acc[nt][reg];
}

// ---------------------------------------------------------------------------
// Workspace layout:
//   [0, 384K)        WB
//   [1M, 1M+64K)     Mf (fp32 M accumulator, zeroed by prep)
//   [2M, 4M)         Q
//   [4M, 6M)         Kt
//   [6M, 8M)         Vt
extern "C" void kernel_launch(void* const* d_in, const int* in_sizes, int n_in,
                              void* d_out, int out_size, void* d_ws, size_t ws_size,
                              hipStream_t stream) {
    const float* idx = (const float*)d_in[0];
    const float* Wq  = (const float*)d_in[1];
    const float* bq  = (const float*)d_in[2];
    const float* Wk  = (const float*)d_in[3];
    const float* bk  = (const float*)d_in[4];
    const float* Wv  = (const float*)d_in[5];
    const float* bv  = (const float*)d_in[6];
    float* out = (float*)d_out;

    char* ws = (char*)d_ws;
    unsigned short* WB = (unsigned short*)(ws);
    float*          Mf = (float*)(ws + (1024u << 10));
    unsigned short* Q  = (unsigned short*)(ws + (2048u << 10));
    unsigned short* Kt = (unsigned short*)(ws + (4096u << 10));
    unsigned short* Vt = (unsigned short*)(ws + (6144u << 10));

    hipLaunchKernelGGL(prep, dim3(96),    dim3(256), 0, stream, Wq, Wk, Wv, WB, Mf);
    hipLaunchKernelGGL(qkv,  dim3(512),   dim3(256), 0, stream,
                       idx, WB, bq, bk, bv, Q, Kt, Vt);
    hipLaunchKernelGGL(ktv,  dim3(32, 4), dim3(256), 0, stream, Kt, Vt, Mf);
    hipLaunchKernelGGL(qm,   dim3(256),   dim3(256), 0, stream, Q, Mf, out);
}